// Round 12
// baseline (152.144 us; speedup 1.0000x reference)
//
#include <hip/hip_runtime.h>

// BCE computed in log2 domain; -ln2 applied at finalize. Focal ALPHA deferred too.
#define LOG2_CLAMP (-144.26950408889634f)   /* -100 / ln(2) */
#define NEG_LN2    (-0.6931471805599453)
#define ALPHA_D    (0.25)
#define NBLOCKS    1024   /* R10: grid size is NOT the limiter (flat 43us at 2048 and 1024).
                             This round: explicit 1-deep prefetch pipeline, all else identical. */

__device__ __forceinline__ void loss_elem(float pr, float tr, float yp, float yt,
                                          float& bsum, float& dsum)
{
    // ---- BCE (log2 domain) ----
    float p = fminf(fmaxf(pr, 0.f), 1.f);
    float t = fminf(fmaxf(tr, 0.f), 1.f);
    float l2p = fmaxf(__log2f(p),       LOG2_CLAMP);   // p=0 -> -inf -> clamp
    float l2q = fmaxf(__log2f(1.f - p), LOG2_CLAMP);
    bsum += t * (l2p - l2q) + l2q;          // * -ln2 at finalize
    // ---- duration focal (ALPHA deferred) ----
    float d = fabsf(yp - yt);
    float r = fminf(d + d, 1.f);            // clip(d/0.5, 0, 1)
    float base = (d < 0.5f) ? (d * d)       // 0.5*d*d/0.5
                            : (d - 0.25f);  // d - 0.5*DELTA
    float c = fminf(fmaxf(rintf(yt), 0.f), 3.f);   // round half-even, clamp [0,3]
    float w = (c == 0.f) ? 1.f : (5.f - c);        // {0,1,2,3} -> {1,4,3,2}
    dsum += ((r * r) * base) * w;
}

#define COMPUTE8(P0,T0,Y0,Z0,P1,T1,Y1,Z1)                      \
    {                                                          \
        float bsum = 0.f, dsum = 0.f;                          \
        loss_elem(P0.x, T0.x, Y0.x, Z0.x, bsum, dsum);         \
        loss_elem(P0.y, T0.y, Y0.y, Z0.y, bsum, dsum);         \
        loss_elem(P0.z, T0.z, Y0.z, Z0.z, bsum, dsum);         \
        loss_elem(P0.w, T0.w, Y0.w, Z0.w, bsum, dsum);         \
        loss_elem(P1.x, T1.x, Y1.x, Z1.x, bsum, dsum);         \
        loss_elem(P1.y, T1.y, Y1.y, Z1.y, bsum, dsum);         \
        loss_elem(P1.z, T1.z, Y1.z, Z1.z, bsum, dsum);         \
        loss_elem(P1.w, T1.w, Y1.w, Z1.w, bsum, dsum);         \
        abce += (double)bsum;                                  \
        adur += (double)dsum;                                  \
    }

// Pass 1: fused streaming; per-block partial pair stored to ws (no atomics).
// Explicit software pipeline: issue iteration k+1's 8 dwordx4 loads BEFORE
// computing iteration k (R10 showed a latency wall independent of HBM/L3
// residency and grid size: dur flat at ~43us, VALU 13%, occ 30-45%).
__global__ __launch_bounds__(256) void loss_main_kernel(
    const float* __restrict__ bp_s, const float* __restrict__ bt_s,
    const float* __restrict__ sp_s, const float* __restrict__ st_s,
    double2* __restrict__ partials, int n)
{
    const int n4 = n >> 2;
    const float4* __restrict__ bp = (const float4*)bp_s;
    const float4* __restrict__ bt = (const float4*)bt_s;
    const float4* __restrict__ sp = (const float4*)sp_s;
    const float4* __restrict__ st = (const float4*)st_s;

    const int stride = gridDim.x * blockDim.x;   // 262144
    const int step   = 2 * stride;
    int i = blockIdx.x * blockDim.x + threadIdx.x;

    double abce = 0.0, adur = 0.0;

    if ((n4 % step) == 0 && n4 >= 2 * step) {
        // fast path (this shape: T = 4 iterations of 2 chunks per array)
        const int T = n4 / step;
        float4 P0 = bp[i],          T0 = bt[i],          Y0 = sp[i],          Z0 = st[i];
        float4 P1 = bp[i + stride], T1 = bt[i + stride], Y1 = sp[i + stride], Z1 = st[i + stride];
        for (int k = 0; k < T - 1; ++k) {
            const int j = i + step;
            // prefetch next iteration's 8 chunks (independent of current compute)
            float4 Q0 = bp[j],          U0 = bt[j],          V0 = sp[j],          W0 = st[j];
            float4 Q1 = bp[j + stride], U1 = bt[j + stride], V1 = sp[j + stride], W1 = st[j + stride];
            COMPUTE8(P0, T0, Y0, Z0, P1, T1, Y1, Z1)
            P0 = Q0; T0 = U0; Y0 = V0; Z0 = W0;
            P1 = Q1; T1 = U1; Y1 = V1; Z1 = W1;
            i = j;
        }
        COMPUTE8(P0, T0, Y0, Z0, P1, T1, Y1, Z1)
    } else {
        // guarded fallback (arbitrary n), R10 structure
        for (; i + stride < n4; i += step) {
            float4 P0 = bp[i],          T0 = bt[i],          Y0 = sp[i],          Z0 = st[i];
            float4 P1 = bp[i + stride], T1 = bt[i + stride], Y1 = sp[i + stride], Z1 = st[i + stride];
            COMPUTE8(P0, T0, Y0, Z0, P1, T1, Y1, Z1)
        }
        for (; i < n4; i += stride) {
            float4 P0 = bp[i], T0 = bt[i], Y0 = sp[i], Z0 = st[i];
            float bsum = 0.f, dsum = 0.f;
            loss_elem(P0.x, T0.x, Y0.x, Z0.x, bsum, dsum);
            loss_elem(P0.y, T0.y, Y0.y, Z0.y, bsum, dsum);
            loss_elem(P0.z, T0.z, Y0.z, Z0.z, bsum, dsum);
            loss_elem(P0.w, T0.w, Y0.w, Z0.w, bsum, dsum);
            abce += (double)bsum;
            adur += (double)dsum;
        }
        const int rem = n - (n4 << 2);
        if (rem && blockIdx.x == 0 && threadIdx.x == 0) {
            float bsum = 0.f, dsum = 0.f;
            for (int k = n4 << 2; k < n; ++k)
                loss_elem(bp_s[k], bt_s[k], sp_s[k], st_s[k], bsum, dsum);
            abce += (double)bsum;
            adur += (double)dsum;
        }
    }

    // wave reduce (64 lanes)
    for (int off = 32; off > 0; off >>= 1) {
        abce += __shfl_down(abce, off);
        adur += __shfl_down(adur, off);
    }
    __shared__ double sb[4], sd[4];
    const int lane = threadIdx.x & 63;
    const int wid  = threadIdx.x >> 6;
    if (lane == 0) { sb[wid] = abce; sd[wid] = adur; }
    __syncthreads();
    if (threadIdx.x == 0)
        partials[blockIdx.x] = make_double2(sb[0] + sb[1] + sb[2] + sb[3],
                                            sd[0] + sd[1] + sd[2] + sd[3]);
}

// Pass 2: one block reduces NBLOCKS partial pairs, writes the 3 outputs.
__global__ __launch_bounds__(256) void loss_finalize_kernel(
    const double2* __restrict__ partials, float* __restrict__ out, double invn)
{
    double abce = 0.0, adur = 0.0;
    for (int i = threadIdx.x; i < NBLOCKS; i += 256) {
        double2 v = partials[i];
        abce += v.x;
        adur += v.y;
    }
    for (int off = 32; off > 0; off >>= 1) {
        abce += __shfl_down(abce, off);
        adur += __shfl_down(adur, off);
    }
    __shared__ double sb[4], sd[4];
    const int lane = threadIdx.x & 63;
    const int wid  = threadIdx.x >> 6;
    if (lane == 0) { sb[wid] = abce; sd[wid] = adur; }
    __syncthreads();
    if (threadIdx.x == 0) {
        double bce = (sb[0] + sb[1] + sb[2] + sb[3]) * NEG_LN2 * invn;
        double dur = (sd[0] + sd[1] + sd[2] + sd[3]) * ALPHA_D * invn;
        out[0] = (float)(bce + dur);
        out[1] = (float)bce;
        out[2] = (float)dur;
    }
}

extern "C" void kernel_launch(void* const* d_in, const int* in_sizes, int n_in,
                              void* d_out, int out_size, void* d_ws, size_t ws_size,
                              hipStream_t stream)
{
    const float* bp = (const float*)d_in[0];
    const float* bt = (const float*)d_in[1];
    const float* sp = (const float*)d_in[2];
    const float* st = (const float*)d_in[3];
    float* out = (float*)d_out;
    double2* partials = (double2*)d_ws;     // NBLOCKS * 16 B = 16 KB scratch

    const int n = in_sizes[0];   // 64 * 131072 = 8,388,608

    // Every partial slot is unconditionally overwritten -> no memset needed.
    loss_main_kernel<<<NBLOCKS, 256, 0, stream>>>(bp, bt, sp, st, partials, n);
    loss_finalize_kernel<<<1, 256, 0, stream>>>(partials, out, 1.0 / (double)n);
}